// Round 16
// baseline (46.859 us; speedup 1.0000x reference)
//
#include <hip/hip_runtime.h>
#include <hip/hip_bf16.h>

#define TOT     2048      // B*SEQ rows
#define INDIM   512
#define OD      256
#define SEQL    1024
#define TQ      512       // out_seq
#define NB      2
#define LN_EPS  1e-5f

#define JSPL    16        // k2 j-split (planes)
#define JW      (OD / JSPL)      // 16 j per k2 block
#define K3SPL   8         // k3 K-split

typedef __attribute__((ext_vector_type(8))) short bf16x8;
typedef __attribute__((ext_vector_type(4))) float f32x4;
typedef __attribute__((ext_vector_type(2))) float f32x2;

__device__ __forceinline__ short f2bf(float f) {
    __hip_bfloat16 h = __float2bfloat16(f);
    return *(short*)&h;
}
__device__ __forceinline__ uint pack2(float a, float b) {
    return (uint)(ushort)f2bf(a) | ((uint)(ushort)f2bf(b) << 16);
}

// ============ shared 64x64 MFMA tile: C = A[rows][k] * B[cols][k]^T ============
// CVT: operands are f32 in global, converted to bf16 during LDS staging.
// ATOMIC: accumulate into C via atomicAdd (commutative) instead of store.
template<bool CVT, bool ATOMIC>
__device__ __forceinline__ void mfma_tile64(
    const void* __restrict__ Av, int lda,
    const void* __restrict__ Bv, int ldb,
    float* __restrict__ C, int ldc,
    int r0, int c0, int k0, int nk)
{
    __shared__ short Al[64][40];   // pad to 40 bf16 (80 B rows, 16B-aligned)
    __shared__ short Bl[64][40];
    const int tid = threadIdx.x;
    const int w   = tid >> 6;
    const int wm  = w >> 1, wn = w & 1;
    const int l   = tid & 63;
    const int lr  = l & 15, lg = l >> 4;
    const int srow = tid >> 2, skg = (tid & 3) * 8;

    f32x4 acc[2][2] = {{{0.f,0.f,0.f,0.f},{0.f,0.f,0.f,0.f}},
                       {{0.f,0.f,0.f,0.f},{0.f,0.f,0.f,0.f}}};

    for (int ks = 0; ks < nk; ++ks) {
        const int kb = k0 + ks * 32;
        __syncthreads();
        if (CVT) {
            const float* Af = (const float*)Av;
            const float* Bf = (const float*)Bv;
            const float* ar = Af + (size_t)(r0 + srow) * lda + kb + skg;
            float4 a0 = *(const float4*)ar, a1 = *(const float4*)(ar + 4);
            *(uint4*)&Al[srow][skg] = make_uint4(pack2(a0.x, a0.y), pack2(a0.z, a0.w),
                                                 pack2(a1.x, a1.y), pack2(a1.z, a1.w));
            const float* br = Bf + (size_t)(c0 + srow) * ldb + kb + skg;
            float4 b0 = *(const float4*)br, b1 = *(const float4*)(br + 4);
            *(uint4*)&Bl[srow][skg] = make_uint4(pack2(b0.x, b0.y), pack2(b0.z, b0.w),
                                                 pack2(b1.x, b1.y), pack2(b1.z, b1.w));
        } else {
            const short* As = (const short*)Av;
            const short* Bs = (const short*)Bv;
            *(bf16x8*)&Al[srow][skg] = *(const bf16x8*)(As + (size_t)(r0 + srow) * lda + kb + skg);
            *(bf16x8*)&Bl[srow][skg] = *(const bf16x8*)(Bs + (size_t)(c0 + srow) * ldb + kb + skg);
        }
        __syncthreads();
        bf16x8 a0 = *(const bf16x8*)&Al[wm * 32 +      lr][lg * 8];
        bf16x8 a1 = *(const bf16x8*)&Al[wm * 32 + 16 + lr][lg * 8];
        bf16x8 b0 = *(const bf16x8*)&Bl[wn * 32 +      lr][lg * 8];
        bf16x8 b1 = *(const bf16x8*)&Bl[wn * 32 + 16 + lr][lg * 8];
        acc[0][0] = __builtin_amdgcn_mfma_f32_16x16x32_bf16(a0, b0, acc[0][0], 0, 0, 0);
        acc[0][1] = __builtin_amdgcn_mfma_f32_16x16x32_bf16(a0, b1, acc[0][1], 0, 0, 0);
        acc[1][0] = __builtin_amdgcn_mfma_f32_16x16x32_bf16(a1, b0, acc[1][0], 0, 0, 0);
        acc[1][1] = __builtin_amdgcn_mfma_f32_16x16x32_bf16(a1, b1, acc[1][1], 0, 0, 0);
    }
    // D: col = lane&15, row = 4*(lane>>4)+reg  [m89-verified]
#pragma unroll
    for (int sm = 0; sm < 2; ++sm)
#pragma unroll
    for (int sn = 0; sn < 2; ++sn)
#pragma unroll
    for (int q = 0; q < 4; ++q) {
        float* dst = C + (size_t)(r0 + wm * 32 + sm * 16 + 4 * lg + q) * ldc
                       + (c0 + wn * 32 + sn * 16 + lr);
        if (ATOMIC) atomicAdd(dst, acc[sm][sn][q]);
        else        *dst = acc[sm][sn][q];
    }
}

// ============ K1: Zp[h] = bf16(x) * bf16(M)^T (K-half h), cvt inline ============
__global__ __launch_bounds__(256, 4) void k1_mfma(
    const float* __restrict__ x, const float* __restrict__ M,
    float* __restrict__ Zp)
{
    mfma_tile64<true, false>(x, INDIM, M, INDIM,
                             Zp + (size_t)blockIdx.z * TOT * OD, OD,
                             blockIdx.x * 64, blockIdx.y * 64, blockIdx.z * 256, 8);
}

// ============ K1b: blocks 0..255: Z = Zp0+Zp1, Zn = LayerNorm(Z);
//   blocks 256..767: ALt = bf16(Linker^T) + zero `out` (for k3 atomics) ====
__global__ __launch_bounds__(256) void k1b_ln(
    const float* __restrict__ Zp,
    const float* __restrict__ gamma, const float* __restrict__ beta,
    float* __restrict__ Z, float* __restrict__ Zn,
    const float* __restrict__ L, short* __restrict__ ALt,
    float* __restrict__ out, int out_size)
{
    const int tid = threadIdx.x;
    if (blockIdx.x >= 256) {
        const int tt = blockIdx.x - 256;    // 512 tiles: 32 s-tiles x 16 t-tiles
        // ---- zero this block's share of out (512 floats) for k3's atomics ----
        *(f32x2*)(out + tt * 512 + tid * 2) = (f32x2){0.f, 0.f};
        if (tt == 0 && tid == 0 && out_size > NB * TQ * OD)
            out[NB * TQ * OD] = (float)TQ;  // second output: out_seq = 512
        // ---- ALt transpose tile (needs nothing from k1) ----
        __shared__ float tl[32][36];
        const int s0 = (tt >> 4) * 32;
        const int t0 = (tt & 15) * 32;
        const int r  = tid >> 3;
        const int c4 = (tid & 7) * 4;
        float4 v = *(const float4*)(L + (size_t)(s0 + r) * TQ + t0 + c4);
        tl[r][c4 + 0] = v.x; tl[r][c4 + 1] = v.y;
        tl[r][c4 + 2] = v.z; tl[r][c4 + 3] = v.w;
        __syncthreads();
        uint lo = pack2(tl[c4 + 0][r], tl[c4 + 1][r]);
        uint hi = pack2(tl[c4 + 2][r], tl[c4 + 3][r]);
        *(uint2*)(ALt + (size_t)(t0 + r) * SEQL + s0 + c4) = make_uint2(lo, hi);
        return;
    }

    const int r0 = blockIdx.x * 8;
    const int c  = tid;

    float acc[8];
#pragma unroll
    for (int r = 0; r < 8; ++r) {
        const size_t i = (size_t)(r0 + r) * OD + c;
        acc[r] = Zp[i] + Zp[(size_t)TOT * OD + i];
    }

    __shared__ float s1[8][4], s2[8][4];
    const int lane = c & 63;
    const int wid  = c >> 6;
#pragma unroll
    for (int r = 0; r < 8; ++r) {
        float s = acc[r], q = acc[r] * acc[r];
#pragma unroll
        for (int off = 32; off > 0; off >>= 1) {
            s += __shfl_xor(s, off, 64);
            q += __shfl_xor(q, off, 64);
        }
        if (lane == 0) { s1[r][wid] = s; s2[r][wid] = q; }
    }
    __syncthreads();
#pragma unroll
    for (int r = 0; r < 8; ++r) {
        float s  = s1[r][0] + s1[r][1] + s1[r][2] + s1[r][3];
        float q  = s2[r][0] + s2[r][1] + s2[r][2] + s2[r][3];
        float mu = s * (1.f / OD);
        float var = q * (1.f / OD) - mu * mu;
        float inv = rsqrtf(var + LN_EPS);
        float z  = acc[r];
        float zn = (z - mu) * inv * gamma[c] + beta[c];
        Z [(size_t)(r0 + r) * OD + c] = z;
        Zn[(size_t)(r0 + r) * OD + c] = zn;
    }
}

// ============ K2 v3: T[k,i] = sum_j Zn[k,j]*P[i,j]*cos(2*pi*k/(i*256+j+2)) ============
// d-recurrence: d_k = P[i,j]*cos(2pi k/p) satisfies d_{k+2} = 2cos(2d)*d_k - d_{k-2};
// P folded into initial conditions -> inner loop = 1 acc-fma + 1 advance-fma per pair.
// Lane owns 32 k (kg = wave) x 2 adjacent i; block 128 thr; tile 64k x 128i x 16j.
__global__ __launch_bounds__(128) void k2_t(
    const float* __restrict__ Zn, const float* __restrict__ P,
    short* __restrict__ Tp)
{
    const int k0 = blockIdx.x * 64;
    const int i0 = blockIdx.y * 128;
    const int j0 = blockIdx.z * JW;

    __shared__ float znT[JW][68];    // [j][k_local]: broadcast rows
    __shared__ float ptT[JW][132];   // [j][i_local]: lane pair -> ds_read_b64

    const int tid = threadIdx.x;
    {   // stage Zn^T: 64 rows x 16 j, threads split j in halves
        const int row = tid & 63;
        const int jh  = (tid >> 6) * 8;
        const float* zr = Zn + (size_t)(k0 + row) * OD + j0 + jh;
        float4 v0 = *(const float4*)(zr);
        float4 v1 = *(const float4*)(zr + 4);
        znT[jh + 0][row] = v0.x; znT[jh + 1][row] = v0.y;
        znT[jh + 2][row] = v0.z; znT[jh + 3][row] = v0.w;
        znT[jh + 4][row] = v1.x; znT[jh + 5][row] = v1.y;
        znT[jh + 6][row] = v1.z; znT[jh + 7][row] = v1.w;
        // stage P^T: 128 i rows x 16 j
        const float* pr = P + (size_t)(i0 + tid) * OD + j0;
        float4 p0 = *(const float4*)(pr);
        float4 p1 = *(const float4*)(pr + 4);
        float4 p2 = *(const float4*)(pr + 8);
        float4 p3 = *(const float4*)(pr + 12);
        ptT[ 0][tid] = p0.x; ptT[ 1][tid] = p0.y; ptT[ 2][tid] = p0.z; ptT[ 3][tid] = p0.w;
        ptT[ 4][tid] = p1.x; ptT[ 5][tid] = p1.y; ptT[ 6][tid] = p1.z; ptT[ 7][tid] = p1.w;
        ptT[ 8][tid] = p2.x; ptT[ 9][tid] = p2.y; ptT[10][tid] = p2.z; ptT[11][tid] = p2.w;
        ptT[12][tid] = p3.x; ptT[13][tid] = p3.y; ptT[14][tid] = p3.z; ptT[15][tid] = p3.w;
    }
    __syncthreads();

    const int kg = tid >> 6;              // wave = k-half
    const int l  = tid & 63;
    const int il = 2 * l;                 // local i pair
    const float kbase = (float)(k0 + kg * 32);
    const float pbA   = (float)((i0 + il) * OD + j0 + 2);     // exact (< 2^24)

    f32x2 accA[16], accB[16];
#pragma unroll
    for (int m = 0; m < 16; ++m) { accA[m] = (f32x2){0.f, 0.f}; accB[m] = (f32x2){0.f, 0.f}; }

    const float* zrow = &znT[0][kg * 32];

    for (int j = 0; j < JW; ++j) {
        f32x2 wp = *(const f32x2*)&ptT[j][il];    // {wA, wB} one b64
        const float pA  = pbA + (float)j;
        const float ipA = __builtin_amdgcn_rcpf(pA);
        const float aA  = __builtin_amdgcn_fractf(kbase * ipA);
        const float c0A = __builtin_amdgcn_cosf(aA);
        const float s0A = __builtin_amdgcn_sinf(aA);
        const float cdA = __builtin_amdgcn_cosf(ipA);
        const float sdA = __builtin_amdgcn_sinf(ipA);
        const float c1A = c0A * cdA - s0A * sdA;
        const float s1A = s0A * cdA + c0A * sdA;
        const float c2A = c1A * cdA - s1A * sdA;
        const float c3A = c2A * cdA - (s1A * cdA + c1A * sdA) * sdA;
        const float r2A = 2.f * (1.f - 2.f * sdA * sdA);
        f32x2 DA_p = {wp.x * c0A, wp.x * c1A};
        f32x2 DA_c = {wp.x * c2A, wp.x * c3A};
        const f32x2 RA = {r2A, r2A};
        const float pB  = pA + 256.f;
        const float ipB = __builtin_amdgcn_rcpf(pB);
        const float aB  = __builtin_amdgcn_fractf(kbase * ipB);
        const float c0B = __builtin_amdgcn_cosf(aB);
        const float s0B = __builtin_amdgcn_sinf(aB);
        const float cdB = __builtin_amdgcn_cosf(ipB);
        const float sdB = __builtin_amdgcn_sinf(ipB);
        const float c1B = c0B * cdB - s0B * sdB;
        const float s1B = s0B * cdB + c0B * sdB;
        const float c2B = c1B * cdB - s1B * sdB;
        const float c3B = c2B * cdB - (s1B * cdB + c1B * sdB) * sdB;
        const float r2B = 2.f * (1.f - 2.f * sdB * sdB);
        f32x2 DB_p = {wp.y * c0B, wp.y * c1B};
        f32x2 DB_c = {wp.y * c2B, wp.y * c3B};
        const f32x2 RB = {r2B, r2B};

        const float* zc = zrow + (size_t)j * 68;
#pragma unroll
        for (int m = 0; m < 8; ++m) {     // 8 x float4 = 32 k = 16 pairs
            float4 z4 = *(const float4*)(zc + 4 * m);
            f32x2 zlo = {z4.x, z4.y};
            f32x2 zhi = {z4.z, z4.w};
            accA[2 * m    ] += zlo * DA_p;
            accB[2 * m    ] += zlo * DB_p;
            f32x2 tA = RA * DA_c - DA_p;  DA_p = DA_c;  DA_c = tA;
            f32x2 tB = RB * DB_c - DB_p;  DB_p = DB_c;  DB_c = tB;
            accA[2 * m + 1] += zhi * DA_p;
            accB[2 * m + 1] += zhi * DB_p;
            tA = RA * DA_c - DA_p;  DA_p = DA_c;  DA_c = tA;
            tB = RB * DB_c - DB_p;  DB_p = DB_c;  DB_c = tB;
        }
    }

    short* Tpl = Tp + (size_t)blockIdx.z * (TOT * OD);
    const int ia = i0 + il;
    const int kb = k0 + kg * 32;
#pragma unroll
    for (int m = 0; m < 16; ++m) {
        *(uint*)(Tpl + (size_t)(kb + 2 * m    ) * OD + ia) = pack2(accA[m].x, accB[m].x);
        *(uint*)(Tpl + (size_t)(kb + 2 * m + 1) * OD + ia) = pack2(accA[m].y, accB[m].y);
    }
}

// ============ K2b: Wt[b][o][s] = bf16(Z + sum Tp) transposed ============
__global__ __launch_bounds__(256) void k2b_w(
    const float* __restrict__ Z, const short* __restrict__ Tp,
    short* __restrict__ Wt)
{
    __shared__ float tl[32][36];
    const int kt0 = blockIdx.x * 32;    // global k = b*1024+s
    const int o0  = blockIdx.y * 32;
    const int tid = threadIdx.x;
    const int r   = tid >> 3;           // 0..31 (kt row)
    const int c4  = (tid & 7) * 4;      // 0..28 (o col)

    const size_t idx = (size_t)(kt0 + r) * OD + o0 + c4;
    float4 z = *(const float4*)(Z + idx);
#pragma unroll
    for (int p = 0; p < JSPL; ++p) {
        uint2 t = *(const uint2*)(Tp + (size_t)p * (TOT * OD) + idx);
        z.x += __uint_as_float(t.x << 16);
        z.y += __uint_as_float(t.x & 0xFFFF0000u);
        z.z += __uint_as_float(t.y << 16);
        z.w += __uint_as_float(t.y & 0xFFFF0000u);
    }
    *(float4*)&tl[r][c4] = z;
    __syncthreads();

    const int ol = tid >> 3;            // 0..31 (o row out)
    const int sc = (tid & 7) * 4;       // 0..28 (s col out)
    const int b  = kt0 >> 10;
    const int sb = kt0 & 1023;
    uint lo = pack2(tl[sc + 0][ol], tl[sc + 1][ol]);
    uint hi = pack2(tl[sc + 2][ol], tl[sc + 3][ol]);
    *(uint2*)(Wt + ((size_t)b * OD + o0 + ol) * SEQL + sb + sc) = make_uint2(lo, hi);
}

// ============ K3: out[b] += ALt * Wt_b^T (s-chunk ksp) via atomicAdd ============
// out zeroed by k1b (3 nodes earlier); 8 commutative adds per element.
__global__ __launch_bounds__(256, 4) void k3_mfma(
    const short* __restrict__ ALt, const short* __restrict__ Wt,
    float* __restrict__ out)
{
    const int b   = blockIdx.z & 1;
    const int ksp = blockIdx.z >> 1;
    mfma_tile64<false, true>(ALt, SEQL, Wt + (size_t)b * OD * SEQL, SEQL,
                             out + (size_t)b * TQ * OD, OD,
                             blockIdx.x * 64, blockIdx.y * 64,
                             ksp * (SEQL / K3SPL), (SEQL / K3SPL) / 32);
}

extern "C" void kernel_launch(void* const* d_in, const int* in_sizes, int n_in,
                              void* d_out, int out_size, void* d_ws, size_t ws_size,
                              hipStream_t stream)
{
    const float* x  = (const float*)d_in[0];
    const float* M  = (const float*)d_in[1];
    const float* P  = (const float*)d_in[2];
    const float* L  = (const float*)d_in[3];
    const float* g  = (const float*)d_in[4];
    const float* be = (const float*)d_in[5];
    float* out = (float*)d_out;

    float* ws_f = (float*)d_ws;
    float* Zp = ws_f;                               // 2 * TOT*OD f32
    float* Z  = Zp + 2 * (size_t)TOT * OD;          // TOT*OD f32
    float* Zn = Z  + (size_t)TOT * OD;              // TOT*OD f32
    short* ALt = (short*)(Zn + (size_t)TOT * OD);
    short* Wt  = ALt + (size_t)TQ * SEQL;
    short* Tp  = Wt  + (size_t)NB * OD * SEQL;      // JSPL * TOT*OD bf16

    k1_mfma<<<dim3(TOT / 64, OD / 64, 2), 256, 0, stream>>>(x, M, Zp);
    k1b_ln<<<768, 256, 0, stream>>>(Zp, g, be, Z, Zn, L, ALt, out, out_size);
    k2_t<<<dim3(TOT / 64, OD / 128, JSPL), 128, 0, stream>>>(Zn, P, Tp);
    k2b_w<<<dim3(TOT / 32, OD / 32), 256, 0, stream>>>(Z, Tp, Wt);
    k3_mfma<<<dim3(TQ / 64, OD / 64, NB * K3SPL), 256, 0, stream>>>(ALt, Wt, out);
}